// Round 3
// baseline (226.718 us; speedup 1.0000x reference)
//
#include <hip/hip_runtime.h>
#include <hip/hip_fp16.h>

#define NMESH 128
#define NMESH2 (128 * 128)
#define NMESH3 (128 * 128 * 128)
#define NPOINTS 100000
#define NCH 16

// ---------------------------------------------------------------------------
// Kernel 1: transpose (C,X,Y,Z) fp32 -> (X,Y,Z,C) fp16, no LDS.
// One thread per spatial index s: 16 coalesced scalar loads (one per channel,
// each wave-instr covers 256 contiguous bytes), pack to 8 u32 in-register,
// write 32 B via two dwordx4.
// ---------------------------------------------------------------------------
__global__ __launch_bounds__(256) void transpose_to_half_v2(
    const float* __restrict__ in,   // [16][2M]
    __half* __restrict__ outT)      // [2M][16]
{
    const int s = blockIdx.x * 256 + threadIdx.x;  // 0 .. 2M-1

    float v[NCH];
#pragma unroll
    for (int c = 0; c < NCH; ++c)
        v[c] = in[(size_t)c * NMESH3 + s];

    uint32_t u[8];
#pragma unroll
    for (int k = 0; k < 8; ++k) {
        u[k] = (uint32_t)__half_as_ushort(__float2half(v[2 * k])) |
               ((uint32_t)__half_as_ushort(__float2half(v[2 * k + 1])) << 16);
    }

    uint4* dst = (uint4*)(outT + (size_t)s * NCH);
    dst[0] = make_uint4(u[0], u[1], u[2], u[3]);
    dst[1] = make_uint4(u[4], u[5], u[6], u[7]);
}

// ---------------------------------------------------------------------------
// Kernel 2: gather. 4 lanes per point; lane handles 4 channels (8 B/tap load).
// 27 independent 8 B loads per thread; coalesced float4 output store.
// ---------------------------------------------------------------------------
__global__ __launch_bounds__(256) void gather_half_v2(
    const __half* __restrict__ meshT,  // [2M][16]
    const float* __restrict__ pts,     // [100000][3]
    float* __restrict__ out)           // [100000][16]
{
    const int tid = blockIdx.x * 256 + threadIdx.x;
    const int p = tid >> 2;
    const int c0 = (tid & 3) * 4;
    if (p >= NPOINTS) return;

    const float SP = 0.1f;
    const float pcx = pts[p * 3 + 0] / SP;
    const float pcy = pts[p * 3 + 1] / SP;
    const float pcz = pts[p * 3 + 2] / SP;

    const int rx = (int)rintf(pcx);
    const int ry = (int)rintf(pcy);
    const int rz = (int)rintf(pcz);

    const float dx = pcx - (float)rx;
    const float dy = pcy - (float)ry;
    const float dz = pcz - (float)rz;

    float wX[3], wY[3], wZ[3];
    wX[0] = (2.0f * dx - 1.0f) * (2.0f * dx - 1.0f) * 0.125f;
    wX[1] = 0.75f - dx * dx;
    wX[2] = (2.0f * dx + 1.0f) * (2.0f * dx + 1.0f) * 0.125f;
    wY[0] = (2.0f * dy - 1.0f) * (2.0f * dy - 1.0f) * 0.125f;
    wY[1] = 0.75f - dy * dy;
    wY[2] = (2.0f * dy + 1.0f) * (2.0f * dy + 1.0f) * 0.125f;
    wZ[0] = (2.0f * dz - 1.0f) * (2.0f * dz - 1.0f) * 0.125f;
    wZ[1] = 0.75f - dz * dz;
    wZ[2] = (2.0f * dz + 1.0f) * (2.0f * dz + 1.0f) * 0.125f;

    // offsets in units of halves
    int xo[3], yo[3], zo[3];
#pragma unroll
    for (int k = 0; k < 3; ++k) {
        xo[k] = ((rx - 1 + k) & (NMESH - 1)) * (NMESH2 * NCH);
        yo[k] = ((ry - 1 + k) & (NMESH - 1)) * (NMESH * NCH);
        zo[k] = ((rz - 1 + k) & (NMESH - 1)) * NCH + c0;
    }

    float acc0 = 0.0f, acc1 = 0.0f, acc2 = 0.0f, acc3 = 0.0f;
#pragma unroll
    for (int a = 0; a < 3; ++a) {
#pragma unroll
        for (int b = 0; b < 3; ++b) {
            const int base = xo[a] + yo[b];
            const float wxy = wX[a] * wY[b];
#pragma unroll
            for (int k = 0; k < 3; ++k) {
                const float2 raw = *(const float2*)(meshT + base + zo[k]);  // 8 B = 4 halves
                const __half2 h01 = *(const __half2*)&raw.x;
                const __half2 h23 = *(const __half2*)&raw.y;
                const float2 f01 = __half22float2(h01);
                const float2 f23 = __half22float2(h23);
                const float w = wxy * wZ[k];
                acc0 = fmaf(f01.x, w, acc0);
                acc1 = fmaf(f01.y, w, acc1);
                acc2 = fmaf(f23.x, w, acc2);
                acc3 = fmaf(f23.y, w, acc3);
            }
        }
    }

    float4 res = make_float4(acc0, acc1, acc2, acc3);
    *(float4*)(out + (size_t)p * NCH + c0) = res;  // coalesced 16 B/lane
}

// ---------------------------------------------------------------------------
// Fallback in case ws_size is too small for the fp16 transposed mesh.
// ---------------------------------------------------------------------------
__global__ __launch_bounds__(256) void mesh_interp_fallback_kernel(
    const float* __restrict__ mesh,
    const float* __restrict__ pts,
    float* __restrict__ out)
{
    const int tid = blockIdx.x * 256 + threadIdx.x;
    const int c = tid & (NCH - 1);
    const int p = tid >> 4;
    if (p >= NPOINTS) return;

    const float SP = 0.1f;
    const float pcx = pts[p * 3 + 0] / SP;
    const float pcy = pts[p * 3 + 1] / SP;
    const float pcz = pts[p * 3 + 2] / SP;

    const int rx = (int)rintf(pcx);
    const int ry = (int)rintf(pcy);
    const int rz = (int)rintf(pcz);

    const float dx = pcx - (float)rx;
    const float dy = pcy - (float)ry;
    const float dz = pcz - (float)rz;

    float wX[3], wY[3], wZ[3];
    wX[0] = (2.0f * dx - 1.0f) * (2.0f * dx - 1.0f) * 0.125f;
    wX[1] = 0.75f - dx * dx;
    wX[2] = (2.0f * dx + 1.0f) * (2.0f * dx + 1.0f) * 0.125f;
    wY[0] = (2.0f * dy - 1.0f) * (2.0f * dy - 1.0f) * 0.125f;
    wY[1] = 0.75f - dy * dy;
    wY[2] = (2.0f * dy + 1.0f) * (2.0f * dy + 1.0f) * 0.125f;
    wZ[0] = (2.0f * dz - 1.0f) * (2.0f * dz - 1.0f) * 0.125f;
    wZ[1] = 0.75f - dz * dz;
    wZ[2] = (2.0f * dz + 1.0f) * (2.0f * dz + 1.0f) * 0.125f;

    int xb[3], yb[3], zi[3];
#pragma unroll
    for (int k = 0; k < 3; ++k) {
        xb[k] = ((rx - 1 + k) & (NMESH - 1)) * NMESH2;
        yb[k] = ((ry - 1 + k) & (NMESH - 1)) * NMESH;
        zi[k] = ((rz - 1 + k) & (NMESH - 1));
    }

    const float* __restrict__ mc = mesh + (size_t)c * NMESH3;
    float acc = 0.0f;
#pragma unroll
    for (int a = 0; a < 3; ++a) {
#pragma unroll
        for (int b = 0; b < 3; ++b) {
            const float* __restrict__ row = mc + xb[a] + yb[b];
            const float wxy = wX[a] * wY[b];
            acc = fmaf(row[zi[0]], wxy * wZ[0], acc);
            acc = fmaf(row[zi[1]], wxy * wZ[1], acc);
            acc = fmaf(row[zi[2]], wxy * wZ[2], acc);
        }
    }
    out[tid] = acc;
}

extern "C" void kernel_launch(void* const* d_in, const int* in_sizes, int n_in,
                              void* d_out, int out_size, void* d_ws, size_t ws_size,
                              hipStream_t stream) {
    const float* mesh = (const float*)d_in[0];
    const float* pts  = (const float*)d_in[1];
    float* out        = (float*)d_out;

    const size_t needed = (size_t)NMESH3 * NCH * sizeof(__half);  // 64 MiB

    if (ws_size >= needed) {
        __half* meshT = (__half*)d_ws;
        transpose_to_half_v2<<<NMESH3 / 256, 256, 0, stream>>>(mesh, meshT);
        const int total = NPOINTS * 4;  // 4 lanes per point
        gather_half_v2<<<(total + 255) / 256, 256, 0, stream>>>(meshT, pts, out);
    } else {
        const int total = NPOINTS * NCH;
        mesh_interp_fallback_kernel<<<(total + 255) / 256, 256, 0, stream>>>(mesh, pts, out);
    }
}